// Round 5
// baseline (165.028 us; speedup 1.0000x reference)
//
#include <hip/hip_runtime.h>
#include <cmath>

// SSIM stability loss: 1 - mean(SSIM(x,y)), 11x11 Gaussian (sigma=1.5), zero SAME
// padding, fp32, 32 x 1 x 512 x 512.
//
// Row-streaming band kernel. Block = 256 threads = 256 columns x 16-row band.
// 26 H-rows (band + 2*5 halo) stream through an 11-row LDS chunk holding (x,y)
// interleaved as float2 (one ds_read_b64 per tap fetches both inputs).
// Horizontal 11-tap conv -> 5 channels per H-row into an 11-deep circular
// register history (packed v2f math -> v_pk_fma_f32); vertical 11-tap conv is
// a register dot-product on row completion. Single dispatch; per-block partial
// -> fp64 atomicAdd, last block finalizes.
//
// R4 -> R5: occupancy was the limiter (20% measured; grid 1024 blocks = only
// 4 blocks/CU offered while LDS/VGPR allow 6). BROWS 32 -> 16 doubles the grid
// to 2048 blocks (8/CU offered, 6/CU resident = 24 waves/CU). Row-halo compute
// rises 1.31x -> 1.625x, a good trade at 34% VALUBusy.

#define IMG   512
#define BCOLS 256
#define BROWS 16
#define NH    26          // H rows per band = BROWS + 10
#define NCHUNK 3          // ceil(26/11)
#define CHR   11          // rows per LDS chunk (== history depth)
#define LCOLS 272         // staged cols per row (mult of 4; covers c0-8 .. c0+263)
#define LUNITS 68         // LCOLS / 4
#define NUNITS (CHR * LUNITS)   // 748 float4-units per chunk
#define NBLOCKS 2048
#define NPIX  8388608.0

typedef float v2f __attribute__((ext_vector_type(2)));

struct GaussW { float w[11]; };

__global__ __launch_bounds__(256)
void ssim_stream_kernel(const float* __restrict__ x, const float* __restrict__ y,
                        double* __restrict__ acc_ws, unsigned long long* __restrict__ ctr,
                        float* __restrict__ out, GaussW gw) {
    __shared__ v2f tile[CHR][LCOLS];      // (x,y) interleaved; 11*272*8 = 23936 B
    __shared__ float wavesum[4];

    const int tid = threadIdx.x;
    const int c0 = blockIdx.x * BCOLS;
    const int r0 = blockIdx.y * BROWS;
    const size_t img_off = (size_t)blockIdx.z * (IMG * IMG);
    const float* __restrict__ xb = x + img_off;
    const float* __restrict__ yb = y + img_off;

    // broadcast weights into packed pairs once
    v2f wp[11];
    #pragma unroll
    for (int k = 0; k < 11; ++k) { wp[k][0] = gw.w[k]; wp[k][1] = gw.w[k]; }

    float4 sxr[3], syr[3];   // staged regs for the next chunk (3 iters x 256 thr >= 748)

    auto load_chunk = [&](int c) {
        #pragma unroll
        for (int it = 0; it < 3; ++it) {
            int idx = tid + it * 256;
            int row = idx / LUNITS;
            int unit = idx - row * LUNITS;
            int gr = r0 - 5 + c * CHR + row;       // global image row
            int gc = c0 - 8 + unit * 4;            // global col of float4 (16B aligned)
            float4 vx = make_float4(0.f, 0.f, 0.f, 0.f);
            float4 vy = vx;
            // gc % 4 == 0, so (unsigned)gc < IMG implies gc+3 <= 511: whole unit in/out.
            if (idx < NUNITS && (unsigned)gr < IMG && (unsigned)gc < IMG) {
                const float* px = xb + (size_t)gr * IMG + gc;
                const float* py = yb + (size_t)gr * IMG + gc;
                vx = *(const float4*)px;
                vy = *(const float4*)py;
            }
            sxr[it] = vx; syr[it] = vy;
        }
    };
    auto store_chunk = [&]() {
        #pragma unroll
        for (int it = 0; it < 3; ++it) {
            int idx = tid + it * 256;
            if (idx < NUNITS) {
                int row = idx / LUNITS;
                int unit = idx - row * LUNITS;
                v2f* dst = &tile[row][unit * 4];
                dst[0] = (v2f){sxr[it].x, syr[it].x};
                dst[1] = (v2f){sxr[it].y, syr[it].y};
                dst[2] = (v2f){sxr[it].z, syr[it].z};
                dst[3] = (v2f){sxr[it].w, syr[it].w};
            }
        }
    };

    v2f hist01[11];    // (hx, hy)
    v2f hist23[11];    // (hxx, hyy)
    float hist4[11];   // hxy
    float lsum = 0.f;
    const float C1 = 1e-4f, C2 = 9e-4f;
    const int ci = tid;   // local output column; taps at tile cols ci+3 .. ci+13

    load_chunk(0);
    store_chunk();
    __syncthreads();

    #pragma unroll 1
    for (int c = 0; c < NCHUNK; ++c) {      // 3 chunks x 11 rows = 33 >= 26
        if (c < NCHUNK - 1) load_chunk(c + 1);  // global loads overlap chunk-c compute

        #pragma unroll
        for (int s = 0; s < CHR; ++s) {     // H-row m = 11c + s; hist slot = s
            if (!(c == 2 && s >= 4)) {      // m < 26 (wave-uniform guard)
                // --- horizontal 11-tap conv, packed channels ---
                v2f h01 = (v2f){0.f, 0.f};
                v2f h23 = (v2f){0.f, 0.f};
                float h4 = 0.f;
                #pragma unroll
                for (int k = 0; k < 11; ++k) {
                    v2f t = tile[s][ci + 3 + k];
                    v2f tt = wp[k] * t;                               // v_pk_mul_f32
                    h01 = __builtin_elementwise_fma(wp[k], t, h01);   // v_pk_fma_f32
                    h23 = __builtin_elementwise_fma(tt, t, h23);      // v_pk_fma_f32
                    h4 = fmaf(tt[0], t[1], h4);                       // wk*x*y
                }
                hist01[s] = h01; hist23[s] = h23; hist4[s] = h4;

                // --- output row o = m-10 completes now (needs m >= 10) ---
                if (c > 0 || s == 10) {
                    // slot of H row o+j is (s+1+j) % 11 (static per s,j)
                    v2f a01 = (v2f){0.f, 0.f};
                    v2f a23 = (v2f){0.f, 0.f};
                    float a4 = 0.f;
                    #pragma unroll
                    for (int j = 0; j < 11; ++j) {
                        const int sl = (s + 1 + j) % 11;
                        a01 = __builtin_elementwise_fma(wp[j], hist01[sl], a01);
                        a23 = __builtin_elementwise_fma(wp[j], hist23[sl], a23);
                        a4 = fmaf(wp[j][0], hist4[sl], a4);
                    }
                    float mx = a01[0], my = a01[1];
                    float mxx = mx * mx, myy = my * my, mxy = mx * my;
                    float sxx = a23[0] - mxx, syy = a23[1] - myy, sxy = a4 - mxy;
                    float num = (2.f * mxy + C1) * (2.f * sxy + C2);
                    float den = (mxx + myy + C1) * (sxx + syy + C2);
                    lsum += num * __builtin_amdgcn_rcpf(den);
                }
            }
        }

        __syncthreads();                    // everyone done reading tile
        if (c < NCHUNK - 1) { store_chunk(); __syncthreads(); }
    }

    // ---- reduction: wave shuffle -> LDS -> block partial -> fp64 atomic ----
    #pragma unroll
    for (int off = 32; off > 0; off >>= 1)
        lsum += __shfl_down(lsum, off, 64);
    if ((tid & 63) == 0) wavesum[tid >> 6] = lsum;
    __syncthreads();
    if (tid == 0) {
        float bs = wavesum[0] + wavesum[1] + wavesum[2] + wavesum[3];
        atomicAdd(acc_ws, (double)bs);
        __threadfence();
        unsigned long long old = atomicAdd(ctr, 1ull);
        if (old == (unsigned long long)(NBLOCKS - 1)) {
            __threadfence();
            double total = atomicAdd(acc_ws, 0.0);   // atomic RMW sees all prior adds
            out[0] = (float)(1.0 - total / NPIX);
        }
    }
}

extern "C" void kernel_launch(void* const* d_in, const int* in_sizes, int n_in,
                              void* d_out, int out_size, void* d_ws, size_t ws_size,
                              hipStream_t stream) {
    const float* x = (const float*)d_in[0];   // heatmap_clean
    const float* y = (const float*)d_in[1];   // heatmap_adv
    float* out = (float*)d_out;
    double* acc = (double*)d_ws;
    unsigned long long* ctr = (unsigned long long*)((char*)d_ws + 8);

    // zero the 16B of accumulator+counter state (capture-safe async memset)
    hipMemsetAsync(d_ws, 0, 16, stream);

    GaussW gw;
    double g[11], s = 0.0;
    for (int i = 0; i < 11; ++i) { double d = i - 5; g[i] = exp(-(d * d) / 4.5); s += g[i]; }
    for (int i = 0; i < 11; ++i) gw.w[i] = (float)(g[i] / s);

    dim3 grid(IMG / BCOLS, IMG / BROWS, 32);   // (2, 32, 32) = 2048 blocks
    ssim_stream_kernel<<<grid, 256, 0, stream>>>(x, y, acc, ctr, out, gw);
}

// Round 6
// 142.477 us; speedup vs baseline: 1.1583x; 1.1583x over previous
//
#include <hip/hip_runtime.h>
#include <cmath>

// SSIM stability loss: 1 - mean(SSIM(x,y)), 11x11 Gaussian (sigma=1.5), zero SAME
// padding, fp32, 32 x 1 x 512 x 512.
//
// R5 -> R6: barrier-free wave-private tiles. R5 falsified the "grid too small"
// theory (2x blocks -> occupancy 20->25% only, dur regressed): the limiter is
// the per-chunk block-wide __syncthreads cadence (vmcnt(0)+lgkmcnt(0) drain
// stalls all 4 waves together). Now each wave owns a private 64-column slice:
// stages its own 11-row chunk into its own LDS region (80 cols of (x,y) v2f,
// 7040 B/wave) and reads only that region. DS ops are in-order within a wave,
// so NO __syncthreads in the main loop at all -- waves drift and cover each
// other's latencies. BROWS back to 32 (1.31x row halo).
//
// Per wave: horizontal 11-tap conv (packed v_pk_fma_f32: (x,y),(xx,yy) pairs +
// scalar xy) per H-row into an 11-deep circular register history; vertical
// 11-tap conv = register dot-product on row completion. Single dispatch;
// per-block partial -> fp64 atomicAdd, last block finalizes.

#define IMG   512
#define BROWS 32
#define NH    42          // H rows per band = BROWS + 10
#define NCHUNK 4          // ceil(42/11)
#define CHR   11          // rows per LDS chunk (== history depth)
#define WCOLS 64          // output columns per wave
#define LCW   80          // staged cols per wave row (covers c0-8 .. c0+71)
#define UPR   20          // float4 units per staged row (LCW/4)
#define NUW   (CHR * UPR) // 220 float4 units per chunk per input per wave
#define NBLOCKS 1024
#define NPIX  8388608.0

typedef float v2f __attribute__((ext_vector_type(2)));

struct GaussW { float w[11]; };

__global__ __launch_bounds__(256)
void ssim_stream_kernel(const float* __restrict__ x, const float* __restrict__ y,
                        double* __restrict__ acc_ws, unsigned long long* __restrict__ ctr,
                        float* __restrict__ out, GaussW gw) {
    __shared__ v2f tile[4][CHR][LCW];     // per-wave private slices; 4*11*80*8 = 28160 B
    __shared__ float wavesum[4];

    const int tid  = threadIdx.x;
    const int lane = tid & 63;
    const int w    = tid >> 6;            // wave id 0..3
    const int c0 = blockIdx.x * 256 + w * WCOLS;   // wave's column base
    const int r0 = blockIdx.y * BROWS;
    const size_t img_off = (size_t)blockIdx.z * (IMG * IMG);
    const float* __restrict__ xb = x + img_off;
    const float* __restrict__ yb = y + img_off;

    // broadcast weights into packed pairs once
    v2f wp[11];
    #pragma unroll
    for (int k = 0; k < 11; ++k) { wp[k][0] = gw.w[k]; wp[k][1] = gw.w[k]; }

    float4 sxr[4], syr[4];   // staged regs for next chunk (4 iters x 64 lanes >= 220)

    auto load_chunk = [&](int c) {
        #pragma unroll
        for (int it = 0; it < 4; ++it) {
            int idx = lane + it * 64;
            int row = idx / UPR;
            int u   = idx - row * UPR;
            int gr = r0 - 5 + c * CHR + row;       // global image row
            int gc = c0 - 8 + u * 4;               // global col of float4 (16B aligned)
            float4 vx = make_float4(0.f, 0.f, 0.f, 0.f);
            float4 vy = vx;
            // gc % 4 == 0, so (unsigned)gc < IMG implies whole float4 in bounds.
            if (idx < NUW && (unsigned)gr < IMG && (unsigned)gc < IMG) {
                const float* px = xb + (size_t)gr * IMG + gc;
                const float* py = yb + (size_t)gr * IMG + gc;
                vx = *(const float4*)px;
                vy = *(const float4*)py;
            }
            sxr[it] = vx; syr[it] = vy;
        }
    };
    auto store_chunk = [&]() {
        #pragma unroll
        for (int it = 0; it < 4; ++it) {
            int idx = lane + it * 64;
            if (idx < NUW) {
                int row = idx / UPR;
                int u   = idx - row * UPR;
                v2f* dst = &tile[w][row][u * 4];
                dst[0] = (v2f){sxr[it].x, syr[it].x};
                dst[1] = (v2f){sxr[it].y, syr[it].y};
                dst[2] = (v2f){sxr[it].z, syr[it].z};
                dst[3] = (v2f){sxr[it].w, syr[it].w};
            }
        }
    };

    v2f hist01[11];    // (hx, hy)
    v2f hist23[11];    // (hxx, hyy)
    float hist4[11];   // hxy
    float lsum = 0.f;
    const float C1 = 1e-4f, C2 = 9e-4f;

    load_chunk(0);
    store_chunk();
    // no barrier: wave reads only its own slice; DS ops are in-order per wave.

    #pragma unroll 1
    for (int c = 0; c < NCHUNK; ++c) {      // 4 chunks x 11 rows = 44 >= 42
        if (c < NCHUNK - 1) load_chunk(c + 1);  // global loads overlap chunk-c compute

        #pragma unroll
        for (int s = 0; s < CHR; ++s) {     // H-row m = 11c + s; hist slot = s
            if (!(c == NCHUNK - 1 && s >= 9)) {   // m < 42 (wave-uniform guard)
                // --- horizontal 11-tap conv, packed channels ---
                v2f h01 = (v2f){0.f, 0.f};
                v2f h23 = (v2f){0.f, 0.f};
                float h4 = 0.f;
                #pragma unroll
                for (int k = 0; k < 11; ++k) {
                    v2f t = tile[w][s][lane + 3 + k];
                    v2f tt = wp[k] * t;                               // v_pk_mul_f32
                    h01 = __builtin_elementwise_fma(wp[k], t, h01);   // v_pk_fma_f32
                    h23 = __builtin_elementwise_fma(tt, t, h23);      // v_pk_fma_f32
                    h4 = fmaf(tt[0], t[1], h4);                       // wk*x*y
                }
                hist01[s] = h01; hist23[s] = h23; hist4[s] = h4;

                // --- output row o = m-10 completes now (needs m >= 10) ---
                if (c > 0 || s == 10) {
                    // slot of H row o+j is (s+1+j) % 11 (static per s,j)
                    v2f a01 = (v2f){0.f, 0.f};
                    v2f a23 = (v2f){0.f, 0.f};
                    float a4 = 0.f;
                    #pragma unroll
                    for (int j = 0; j < 11; ++j) {
                        const int sl = (s + 1 + j) % 11;
                        a01 = __builtin_elementwise_fma(wp[j], hist01[sl], a01);
                        a23 = __builtin_elementwise_fma(wp[j], hist23[sl], a23);
                        a4 = fmaf(wp[j][0], hist4[sl], a4);
                    }
                    float mx = a01[0], my = a01[1];
                    float mxx = mx * mx, myy = my * my, mxy = mx * my;
                    float sxx = a23[0] - mxx, syy = a23[1] - myy, sxy = a4 - mxy;
                    float num = (2.f * mxy + C1) * (2.f * sxy + C2);
                    float den = (mxx + myy + C1) * (sxx + syy + C2);
                    lsum += num * __builtin_amdgcn_rcpf(den);
                }
            }
        }

        // ds_writes of chunk c+1 follow all ds_reads of chunk c in program
        // order; same-wave DS ops execute in order -> no hazard, no barrier.
        if (c < NCHUNK - 1) store_chunk();
    }

    // ---- reduction: wave shuffle -> LDS -> block partial -> fp64 atomic ----
    #pragma unroll
    for (int off = 32; off > 0; off >>= 1)
        lsum += __shfl_down(lsum, off, 64);
    if (lane == 0) wavesum[w] = lsum;
    __syncthreads();                       // only barrier in the kernel
    if (tid == 0) {
        float bs = wavesum[0] + wavesum[1] + wavesum[2] + wavesum[3];
        atomicAdd(acc_ws, (double)bs);
        __threadfence();
        unsigned long long old = atomicAdd(ctr, 1ull);
        if (old == (unsigned long long)(NBLOCKS - 1)) {
            __threadfence();
            double total = atomicAdd(acc_ws, 0.0);   // atomic RMW sees all prior adds
            out[0] = (float)(1.0 - total / NPIX);
        }
    }
}

extern "C" void kernel_launch(void* const* d_in, const int* in_sizes, int n_in,
                              void* d_out, int out_size, void* d_ws, size_t ws_size,
                              hipStream_t stream) {
    const float* x = (const float*)d_in[0];   // heatmap_clean
    const float* y = (const float*)d_in[1];   // heatmap_adv
    float* out = (float*)d_out;
    double* acc = (double*)d_ws;
    unsigned long long* ctr = (unsigned long long*)((char*)d_ws + 8);

    // zero the 16B of accumulator+counter state (capture-safe async memset)
    hipMemsetAsync(d_ws, 0, 16, stream);

    GaussW gw;
    double g[11], s = 0.0;
    for (int i = 0; i < 11; ++i) { double d = i - 5; g[i] = exp(-(d * d) / 4.5); s += g[i]; }
    for (int i = 0; i < 11; ++i) gw.w[i] = (float)(g[i] / s);

    dim3 grid(2, IMG / BROWS, 32);   // (2, 16, 32) = 1024 blocks
    ssim_stream_kernel<<<grid, 256, 0, stream>>>(x, y, acc, ctr, out, gw);
}